// Round 8
// baseline (3327.570 us; speedup 1.0000x reference)
//
#include <hip/hip_runtime.h>
#include <hip/hip_bf16.h>
#include <stdint.h>

// Problem constants
#define B_  64
#define S_  512
#define E_  300
#define H_  256
#define T_  (B_*S_)     // 32768 tokens
#define G4H 1024        // 4*H gate rows per direction

using half8  = __attribute__((ext_vector_type(8))) _Float16;
using half4  = __attribute__((ext_vector_type(4))) _Float16;
using float4v = __attribute__((ext_vector_type(4))) float;

union H2 { _Float16 h[2]; uint32_t u; };

__device__ inline float sigm(float x) { return 1.f / (1.f + __expf(-x)); }
__device__ inline float tanhf_(float x) {
  float cx = fminf(fmaxf(x, -15.f), 15.f);
  float e = __expf(2.f * cx);
  return (e - 1.f) / (e + 1.f);
}

// raw barrier: drains LDS only, keeps global stores/loads in flight
#define BARRIER() asm volatile("s_waitcnt lgkmcnt(0)\n\ts_barrier" ::: "memory")

// 3x16B L1-bypassed loads (served by local L2), single waitcnt
__device__ inline void ld3_sc0(const uint64_t* p0, const uint64_t* p1,
                               const uint64_t* p2, uint4& a, uint4& b, uint4& c) {
  asm volatile(
      "global_load_dwordx4 %0, %3, off sc0\n\t"
      "global_load_dwordx4 %1, %4, off sc0\n\t"
      "global_load_dwordx4 %2, %5, off sc0\n\t"
      "s_waitcnt vmcnt(0)"
      : "=&v"(a), "=&v"(b), "=&v"(c)
      : "v"(p0), "v"(p1), "v"(p2) : "memory");
}
// 8B L1-bypassed store (fire-and-forget). uint64_t input OK; vector inputs
// hit LLVM "indirect register inputs" limitation.
__device__ inline void st_sc0(uint64_t* p, uint64_t v) {
  asm volatile("global_store_dwordx2 %0, %1, off sc0" :: "v"(p), "v"(v) : "memory");
}
// Un-rematerializable 16B load: asm def forces true register residency
// (compiler cannot re-execute a volatile asm to recompute the value).
__device__ inline uint4 ldx4_pin(const _Float16* p) {
  uint4 r;
  asm volatile("global_load_dwordx4 %0, %1, off\n\ts_waitcnt vmcnt(0)"
               : "=v"(r) : "v"(p));
  return r;
}

// ---------------------------------------------------------------------------
// Prep kernels (unchanged)
// ---------------------------------------------------------------------------
__global__ __launch_bounds__(256) void k_prep_wih(const float* __restrict__ wf,
    const float* __restrict__ wb, _Float16* __restrict__ Bt,
    int KIN, int KP, int total)
{
  int idx = blockIdx.x * 256 + threadIdx.x;
  if (idx >= total) return;
  int n = idx / KP, k = idx % KP;
  int dd = n >> 10, nn = n & 1023;
  int row = (nn & 3) * 256 + (nn >> 2);
  const float* src = dd ? wb : wf;
  Bt[idx] = (_Float16)(k < KIN ? src[row * KIN + k] : 0.f);
}

__global__ __launch_bounds__(256) void k_prep_whh(const float* __restrict__ wf,
    const float* __restrict__ wb, _Float16* __restrict__ Wr)
{
  int idx = blockIdx.x * 256 + threadIdx.x;     // 0 .. 2*1024*256-1
  int dd = idx >> 18;
  int rem = idx & 262143;
  int n = rem >> 8, k = rem & 255;
  int row = (n & 3) * 256 + (n >> 2);
  Wr[idx] = (_Float16)((dd ? wb : wf)[row * 256 + k]);
}

__global__ void k_prep_bias(const float* __restrict__ bif, const float* __restrict__ bhf,
    const float* __restrict__ bib, const float* __restrict__ bhb, float* __restrict__ bias)
{
  int n = blockIdx.x * 256 + threadIdx.x;       // 0..2047
  int dd = n >> 10, nn = n & 1023;
  int row = (nn & 3) * 256 + (nn >> 2);
  bias[n] = dd ? (bib[row] + bhb[row]) : (bif[row] + bhf[row]);
}

__global__ __launch_bounds__(256) void k_gather(const int* __restrict__ ids,
    const float* __restrict__ emb, _Float16* __restrict__ xbf)
{
  int idx = blockIdx.x * 256 + threadIdx.x;     // T*40 threads, 8 f16 each
  int tt = idx / 40;
  int ch = idx % 40;
  int b = tt & 63, s = tt >> 6;
  int id = ids[b * S_ + s];
  const float* src = emb + (size_t)id * E_ + ch * 8;
  half8 v;
#pragma unroll
  for (int e = 0; e < 8; ++e) {
    int k = ch * 8 + e;
    v[e] = (_Float16)(k < E_ ? src[e] : 0.f);
  }
  *(half8*)(xbf + (size_t)tt * 320 + ch * 8) = v;
}

// ---------------------------------------------------------------------------
// Projection GEMM (unchanged): gx[d][t][b][n'] = A @ Bt^T + bias
// ---------------------------------------------------------------------------
template<int K>
__global__ __launch_bounds__(256) void k_gemm(const _Float16* __restrict__ A,
    const _Float16* __restrict__ Bt, const float* __restrict__ bias,
    _Float16* __restrict__ gx)
{
  __shared__ _Float16 sA[128 * 72];
  __shared__ _Float16 sB[128 * 72];
  const int tid = threadIdx.x;
  const int t0 = blockIdx.y * 128;
  const int n0 = blockIdx.x * 128;
  const int lane = tid & 63, wid = tid >> 6;
  const int l15 = lane & 15, q = lane >> 4;
  const int wm = wid & 1, wn = wid >> 1;

  float4v acc[4][4] = {};

  for (int kt = 0; kt < K / 64; ++kt) {
    __syncthreads();
#pragma unroll
    for (int c = 0; c < 4; ++c) {
      int f = tid * 4 + c;
      int row = f >> 3, seg = f & 7;
      *(half8*)&sA[row * 72 + seg * 8] =
          *(const half8*)(A + (size_t)(t0 + row) * K + kt * 64 + seg * 8);
      *(half8*)&sB[row * 72 + seg * 8] =
          *(const half8*)(Bt + (size_t)(n0 + row) * K + kt * 64 + seg * 8);
    }
    __syncthreads();
#pragma unroll
    for (int kk = 0; kk < 2; ++kk) {
      half8 a[4], b[4];
#pragma unroll
      for (int mt = 0; mt < 4; ++mt)
        a[mt] = *(const half8*)&sA[(wm * 64 + mt * 16 + l15) * 72 + kk * 32 + q * 8];
#pragma unroll
      for (int nt = 0; nt < 4; ++nt)
        b[nt] = *(const half8*)&sB[(wn * 64 + nt * 16 + l15) * 72 + kk * 32 + q * 8];
#pragma unroll
      for (int mt = 0; mt < 4; ++mt)
#pragma unroll
        for (int nt = 0; nt < 4; ++nt)
          acc[mt][nt] = __builtin_amdgcn_mfma_f32_16x16x32_f16(a[mt], b[nt], acc[mt][nt], 0, 0, 0);
    }
  }

#pragma unroll
  for (int mt = 0; mt < 4; ++mt) {
#pragma unroll
    for (int nt = 0; nt < 4; ++nt) {
      int token = t0 + wm * 64 + mt * 16 + q * 4;
      int n = n0 + wn * 64 + nt * 16 + l15;
      float bs = bias[n];
      size_t base = (size_t)(n >> 10) * ((size_t)T_ * G4H) + (size_t)token * G4H + (n & 1023);
#pragma unroll
      for (int r = 0; r < 4; ++r)
        gx[base + (size_t)r * G4H] = (_Float16)(acc[mt][nt][r] + bs);
    }
  }
}

// ---------------------------------------------------------------------------
// Persistent recurrence (fan-in 4) — R7 structure with:
//  * weights truly pinned in VGPRs (asm-def loads, un-rematerializable)
//  * gx prefetched one step ahead (latency hidden behind MFMA+epilogue)
// Dual channel h-exchange as R7 (sc0 fast + relaxed agent slow), 2-slot
// parity ping-pong, tag-in-word.
// ---------------------------------------------------------------------------
template<int LAYER>
__global__ __launch_bounds__(256, 1) void k_rec(const _Float16* __restrict__ gx,
    const _Float16* __restrict__ Wr, uint64_t* __restrict__ hxf,
    uint64_t* __restrict__ hxs, _Float16* __restrict__ h1bf,
    float* __restrict__ pd2, const float* __restrict__ w_lin)
{
  const int bx = blockIdx.x;
  const int cg = bx & 7, rg = bx >> 3;
  const int d = cg >> 2, g = cg & 3;
  const int tid = threadIdx.x;
  const int lane = tid & 63, wv = tid >> 6;
  const int l15 = lane & 15, q = lane >> 4;
  const int b0g = g * 16;           // global batch base
  const int n0g = rg * 256;         // gate-row base within direction

  __shared__ _Float16 hstage[16 * 288];   // h(t) [b 16][k 256], pad->288
  __shared__ float    preS[16 * 260];     // preact [b 16][row 256], pad->260

  // zero hstage (h(0) = 0)
  for (int i = tid; i < 16 * 144; i += 256)
    ((uint32_t*)hstage)[i] = 0u;

  // ---- weight fragments: asm-def loads -> MUST stay in registers ----
  uint4 wreg[4][8];
#pragma unroll
  for (int nt = 0; nt < 4; ++nt)
#pragma unroll
    for (int kt = 0; kt < 8; ++kt)
      wreg[nt][kt] = ldx4_pin(Wr +
          (size_t)(d * G4H + n0g + wv * 64 + nt * 16 + l15) * H_ + kt * 32 + q * 8);

  // epilogue-role constants: thread owns 4 cells (batch bl, j = jg..jg+3)
  const int bl = tid >> 4;                  // 0..15
  const int jl4 = (tid & 15) * 4;           // local j within rg's 64
  const int bglob = b0g + bl;
  const int jg = rg * 64 + jl4;
  float wl[4];
#pragma unroll
  for (int cc = 0; cc < 4; ++cc) wl[cc] = w_lin[jg + cc];
  float creg[4] = {0.f, 0.f, 0.f, 0.f};

  uint64_t* fbase = hxf + (size_t)cg * 2 * 2048;
  uint64_t* sbase = hxs + (size_t)cg * 2 * 2048;
  const int off2 = tid * 2;
  const int q2a = (rg + 1) & 3, q2b = (rg + 2) & 3, q2c = (rg + 3) & 3;

  // gx pipeline: load step-0 value up front (latency exposed once)
  half8 gxa, gxb;
  {
    const int time0 = d ? (S_ - 1) : 0;
    const _Float16* gp = gx + ((size_t)d * T_ + (size_t)time0 * B_ + bglob) * G4H
                           + n0g + (tid & 15) * 16;
    gxa = *(const half8*)(gp);
    gxb = *(const half8*)(gp + 8);
  }

  for (int t = 0; t < S_; ++t) {
    const int time = d ? (S_ - 1 - t) : t;

    if (t > 0) {
      const uint64_t* fs = fbase + (size_t)(t & 1) * 2048;
      const uint64_t* ss = sbase + (size_t)(t & 1) * 2048;
      const uint32_t tt = (uint32_t)t;
      uint32_t dat[6];
      unsigned pend = 0x3fu;
      int round = 0;
      while (pend) {
        uint4 A, Bv, C;
        ld3_sc0(fs + q2a * 512 + off2, fs + q2b * 512 + off2,
                fs + q2c * 512 + off2, A, Bv, C);
        if ((pend & 1u)  && A.y  == tt) { dat[0] = A.x;  pend &= ~1u; }
        if ((pend & 2u)  && A.w  == tt) { dat[1] = A.z;  pend &= ~2u; }
        if ((pend & 4u)  && Bv.y == tt) { dat[2] = Bv.x; pend &= ~4u; }
        if ((pend & 8u)  && Bv.w == tt) { dat[3] = Bv.z; pend &= ~8u; }
        if ((pend & 16u) && C.y  == tt) { dat[4] = C.x;  pend &= ~16u; }
        if ((pend & 32u) && C.w  == tt) { dat[5] = C.z;  pend &= ~32u; }
        if (pend && ((++round & 3) == 0)) {
          const int wq[3] = {q2a, q2b, q2c};
#pragma unroll
          for (int k3 = 0; k3 < 3; ++k3)
#pragma unroll
            for (int j = 0; j < 2; ++j) {
              int w = k3 * 2 + j;
              if (pend & (1u << w)) {
                uint64_t v = __hip_atomic_load(ss + wq[k3] * 512 + off2 + j,
                                               __ATOMIC_RELAXED, __HIP_MEMORY_SCOPE_AGENT);
                if ((uint32_t)(v >> 32) == tt) { dat[w] = (uint32_t)v; pend &= ~(1u << w); }
              }
            }
        }
      }
      // stage foreign quarters into hstage
      const int sb = tid >> 4, jp = (tid & 15) * 2;
      uint2 va; va.x = dat[0]; va.y = dat[1];
      uint2 vb; vb.x = dat[2]; vb.y = dat[3];
      uint2 vc; vc.x = dat[4]; vc.y = dat[5];
      *(uint2*)&((uint32_t*)hstage)[sb * 144 + q2a * 32 + jp] = va;
      *(uint2*)&((uint32_t*)hstage)[sb * 144 + q2b * 32 + jp] = vb;
      *(uint2*)&((uint32_t*)hstage)[sb * 144 + q2c * 32 + jp] = vc;
    }
    BARRIER();   // hstage complete (init/own-quarter + staged foreign)

    // ---- prefetch gx(t+1): in flight across MFMA+epilogue ----
    half8 gxa_n, gxb_n;
    {
      const int tn = (t + 1 < S_) ? t + 1 : t;
      const int timen = d ? (S_ - 1 - tn) : tn;
      const _Float16* gp = gx + ((size_t)d * T_ + (size_t)timen * B_ + bglob) * G4H
                             + n0g + (tid & 15) * 16;
      gxa_n = *(const half8*)(gp);
      gxb_n = *(const half8*)(gp + 8);
    }

    // ---- MFMA: pre[b 16][rows 256] = h(t) @ Wq^T (weights in VGPRs) ----
    float4v acc[4] = {};
#pragma unroll
    for (int kt = 0; kt < 8; ++kt) {
      half8 a = *(const half8*)&hstage[l15 * 288 + kt * 32 + q * 8];
#pragma unroll
      for (int nt = 0; nt < 4; ++nt)
        acc[nt] = __builtin_amdgcn_mfma_f32_16x16x32_f16(
            a, __builtin_bit_cast(half8, wreg[nt][kt]), acc[nt], 0, 0, 0);
    }
#pragma unroll
    for (int nt = 0; nt < 4; ++nt)
#pragma unroll
      for (int r = 0; r < 4; ++r)
        preS[(q * 4 + r) * 260 + wv * 64 + nt * 16 + l15] = acc[nt][r];
    BARRIER();   // preS ready; hstage consumed

    // ---- epilogue: 4 cells per thread ----
    half4 hv4;
    float partial = 0.f;
#pragma unroll
    for (int cc = 0; cc < 4; ++cc) {
      float4v p = *(const float4v*)&preS[bl * 260 + (jl4 + cc) * 4];
      float gxi = (float)(cc < 2 ? gxa[cc * 4 + 0] : gxb[(cc - 2) * 4 + 0]);
      float gxf = (float)(cc < 2 ? gxa[cc * 4 + 1] : gxb[(cc - 2) * 4 + 1]);
      float gxg = (float)(cc < 2 ? gxa[cc * 4 + 2] : gxb[(cc - 2) * 4 + 2]);
      float gxo = (float)(cc < 2 ? gxa[cc * 4 + 3] : gxb[(cc - 2) * 4 + 3]);
      float gi = p[0] + gxi, gf = p[1] + gxf, gg = p[2] + gxg, go = p[3] + gxo;
      float cv = sigm(gf) * creg[cc] + sigm(gi) * tanhf_(gg);
      float hv = sigm(go) * tanhf_(cv);
      creg[cc] = cv;
      hv4[cc] = (_Float16)hv;
      if (LAYER == 1) partial += 0.5f * hv * wl[cc];
    }

    // publish FIRST (partner's critical path): fast 2x8B sc0 + slow 2x8B agent
    {
      H2 p0; p0.h[0] = hv4[0]; p0.h[1] = hv4[1];
      H2 p1; p1.h[0] = hv4[2]; p1.h[1] = hv4[3];
      uint32_t tg = (uint32_t)(t + 1);
      uint64_t w0 = ((uint64_t)tg << 32) | p0.u;   // dwordx2: [data, tag]
      uint64_t w1 = ((uint64_t)tg << 32) | p1.u;
      uint64_t* fd = fbase + (size_t)((t + 1) & 1) * 2048 + rg * 512 + off2;
      st_sc0(fd + 0, w0);
      st_sc0(fd + 1, w1);
      uint64_t* sd = sbase + (size_t)((t + 1) & 1) * 2048 + rg * 512 + off2;
      __hip_atomic_store(sd + 0, w0, __ATOMIC_RELAXED, __HIP_MEMORY_SCOPE_AGENT);
      __hip_atomic_store(sd + 1, w1, __ATOMIC_RELAXED, __HIP_MEMORY_SCOPE_AGENT);
    }

    // own quarter into LDS for next step (ordered by next BARRIER)
    *(half4*)&hstage[bl * 288 + jg] = hv4;

    if (LAYER == 0) {
      *(half4*)(h1bf + ((size_t)time * B_ + bglob) * 512 + d * H_ + jg) = hv4;
    } else {
      partial += __shfl_xor(partial, 1);
      partial += __shfl_xor(partial, 2);
      partial += __shfl_xor(partial, 4);
      partial += __shfl_xor(partial, 8);
      if ((tid & 15) == 0)
        atomicAdd(pd2 + ((size_t)d * B_ + bglob) * S_ + time, partial);
    }

    gxa = gxa_n; gxb = gxb_n;
  }
}

// scores + masked-MSE loss
__global__ __launch_bounds__(256) void k_final(const float* __restrict__ pd2,
    const float* __restrict__ labels, const int* __restrict__ masks,
    const float* __restrict__ b_lin, float* __restrict__ out)
{
  int b = blockIdx.x;
  int tid = threadIdx.x;
  float bl = b_lin[0];
  float se = 0.f, sm = 0.f;
  for (int s = tid; s < S_; s += 256) {
    float p = pd2[(size_t)b * S_ + s] + pd2[(size_t)(B_ + b) * S_ + s];
    float sc = sigm(p + bl);
    out[b * S_ + s] = sc;
    float m = (float)masks[b * S_ + s];
    float e = sc - labels[b * S_ + s];
    se += e * e * m;
    sm += m;
  }
  for (int off = 1; off < 64; off <<= 1) {
    se += __shfl_xor(se, off);
    sm += __shfl_xor(sm, off);
  }
  __shared__ float rs[4], rm[4];
  int wid = tid >> 6;
  if ((tid & 63) == 0) { rs[wid] = se; rm[wid] = sm; }
  __syncthreads();
  if (tid == 0) {
    float te = 0.f, tm = 0.f;
    for (int w = 0; w < 4; ++w) { te += rs[w]; tm += rm[w]; }
    atomicAdd(out + T_, (te / tm) * (1.f / 64.f));
  }
}

// ---------------------------------------------------------------------------
extern "C" void kernel_launch(void* const* d_in, const int* in_sizes, int n_in,
                              void* d_out, int out_size, void* d_ws, size_t ws_size,
                              hipStream_t stream)
{
  (void)in_sizes; (void)n_in; (void)out_size; (void)ws_size;
  const int*   ids    = (const int*)d_in[0];
  const float* labels = (const float*)d_in[1];
  const int*   masks  = (const int*)d_in[2];
  const float* emb    = (const float*)d_in[3];
  const float* w_ih_0f = (const float*)d_in[4];
  const float* w_hh_0f = (const float*)d_in[5];
  const float* b_ih_0f = (const float*)d_in[6];
  const float* b_hh_0f = (const float*)d_in[7];
  const float* w_ih_0b = (const float*)d_in[8];
  const float* w_hh_0b = (const float*)d_in[9];
  const float* b_ih_0b = (const float*)d_in[10];
  const float* b_hh_0b = (const float*)d_in[11];
  const float* w_ih_1f = (const float*)d_in[12];
  const float* w_hh_1f = (const float*)d_in[13];
  const float* b_ih_1f = (const float*)d_in[14];
  const float* b_hh_1f = (const float*)d_in[15];
  const float* w_ih_1b = (const float*)d_in[16];
  const float* w_hh_1b = (const float*)d_in[17];
  const float* b_ih_1b = (const float*)d_in[18];
  const float* b_hh_1b = (const float*)d_in[19];
  const float* w_lin   = (const float*)d_in[20];
  const float* b_lin   = (const float*)d_in[21];
  float* out = (float*)d_out;

  char* ws = (char*)d_ws;
  size_t off = 0;
  auto alloc = [&](size_t bytes) -> char* {
    char* p = ws + off;
    off += (bytes + 255) & ~(size_t)255;
    return p;
  };
  _Float16* xbf   = (_Float16*)alloc((size_t)T_ * 320 * 2);        // 21 MB
  _Float16* h1bf  = (_Float16*)alloc((size_t)T_ * 512 * 2);        // 33.5 MB
  _Float16* gx    = (_Float16*)alloc((size_t)2 * T_ * G4H * 2);    // 134 MB
  _Float16* Bt0   = (_Float16*)alloc((size_t)2048 * 320 * 2);
  _Float16* Bt1   = (_Float16*)alloc((size_t)2048 * 512 * 2);
  _Float16* Wr0   = (_Float16*)alloc((size_t)2 * G4H * H_ * 2);
  _Float16* Wr1   = (_Float16*)alloc((size_t)2 * G4H * H_ * 2);
  float*    bias0 = (float*)alloc(2048 * 4);
  float*    bias1 = (float*)alloc(2048 * 4);
  uint64_t* hxf0  = (uint64_t*)alloc((size_t)8 * 2 * 2048 * 8);    // 256 KB
  uint64_t* hxs0  = (uint64_t*)alloc((size_t)8 * 2 * 2048 * 8);
  uint64_t* hxf1  = (uint64_t*)alloc((size_t)8 * 2 * 2048 * 8);
  uint64_t* hxs1  = (uint64_t*)alloc((size_t)8 * 2 * 2048 * 8);
  float*    pd2   = (float*)alloc((size_t)2 * B_ * S_ * 4);        // 256 KB

  // prep
  k_prep_wih<<<(2048 * 320) / 256, 256, 0, stream>>>(w_ih_0f, w_ih_0b, Bt0, 300, 320, 2048 * 320);
  k_prep_wih<<<(2048 * 512) / 256, 256, 0, stream>>>(w_ih_1f, w_ih_1b, Bt1, 512, 512, 2048 * 512);
  k_prep_whh<<<524288 / 256, 256, 0, stream>>>(w_hh_0f, w_hh_0b, Wr0);
  k_prep_whh<<<524288 / 256, 256, 0, stream>>>(w_hh_1f, w_hh_1b, Wr1);
  k_prep_bias<<<8, 256, 0, stream>>>(b_ih_0f, b_hh_0f, b_ih_0b, b_hh_0b, bias0);
  k_prep_bias<<<8, 256, 0, stream>>>(b_ih_1f, b_hh_1f, b_ih_1b, b_hh_1b, bias1);
  k_gather<<<(T_ * 40) / 256, 256, 0, stream>>>(ids, emb, xbf);

  hipMemsetAsync(hxf0, 0, (size_t)8 * 2 * 2048 * 8, stream);
  hipMemsetAsync(hxs0, 0, (size_t)8 * 2 * 2048 * 8, stream);
  hipMemsetAsync(hxf1, 0, (size_t)8 * 2 * 2048 * 8, stream);
  hipMemsetAsync(hxs1, 0, (size_t)8 * 2 * 2048 * 8, stream);
  hipMemsetAsync(pd2, 0, (size_t)2 * B_ * S_ * 4, stream);
  hipMemsetAsync((char*)d_out + (size_t)T_ * 4, 0, 4, stream);

  // layer 0
  k_gemm<320><<<dim3(16, 256), 256, 0, stream>>>(xbf, Bt0, bias0, gx);
  k_rec<0><<<32, 256, 0, stream>>>(gx, Wr0, hxf0, hxs0, h1bf, pd2, w_lin);

  // layer 1
  k_gemm<512><<<dim3(16, 256), 256, 0, stream>>>(h1bf, Bt1, bias1, gx);
  k_rec<1><<<32, 256, 0, stream>>>(gx, Wr1, hxf1, hxs1, h1bf, pd2, w_lin);

  k_final<<<64, 256, 0, stream>>>(pd2, labels, masks, b_lin, out);
}

// Round 9
// 3297.258 us; speedup vs baseline: 1.0092x; 1.0092x over previous
//
#include <hip/hip_runtime.h>
#include <hip/hip_bf16.h>
#include <stdint.h>

// Problem constants
#define B_  64
#define S_  512
#define E_  300
#define H_  256
#define T_  (B_*S_)     // 32768 tokens
#define G4H 1024        // 4*H gate rows per direction

using half8  = __attribute__((ext_vector_type(8))) _Float16;
using half4  = __attribute__((ext_vector_type(4))) _Float16;
using float4v = __attribute__((ext_vector_type(4))) float;

union H2 { _Float16 h[2]; uint32_t u; };

__device__ inline float sigm(float x) { return 1.f / (1.f + __expf(-x)); }
__device__ inline float tanhf_(float x) {
  float cx = fminf(fmaxf(x, -15.f), 15.f);
  float e = __expf(2.f * cx);
  return (e - 1.f) / (e + 1.f);
}

// raw barrier: drains LDS only, keeps global stores/loads in flight
#define BARRIER() asm volatile("s_waitcnt lgkmcnt(0)\n\ts_barrier" ::: "memory")

// 3x16B L1-bypassed loads (served by local L2), single waitcnt
__device__ inline void ld3_sc0(const uint64_t* p0, const uint64_t* p1,
                               const uint64_t* p2, uint4& a, uint4& b, uint4& c) {
  asm volatile(
      "global_load_dwordx4 %0, %3, off sc0\n\t"
      "global_load_dwordx4 %1, %4, off sc0\n\t"
      "global_load_dwordx4 %2, %5, off sc0\n\t"
      "s_waitcnt vmcnt(0)"
      : "=&v"(a), "=&v"(b), "=&v"(c)
      : "v"(p0), "v"(p1), "v"(p2) : "memory");
}
// 8B L1-bypassed store (fire-and-forget)
__device__ inline void st_sc0(uint64_t* p, uint64_t v) {
  asm volatile("global_store_dwordx2 %0, %1, off sc0" :: "v"(p), "v"(v) : "memory");
}
// Un-rematerializable 16B load (weight residency)
__device__ inline uint4 ldx4_pin(const _Float16* p) {
  uint4 r;
  asm volatile("global_load_dwordx4 %0, %1, off\n\ts_waitcnt vmcnt(0)"
               : "=v"(r) : "v"(p));
  return r;
}
// physical XCD id of the executing CU [measured: learn_hip m09]
__device__ inline int xcc_id() {
  int x;
  asm volatile("s_getreg_b32 %0, hwreg(HW_REG_XCC_ID, 0, 32)" : "=s"(x));
  return x & 7;
}

// ---------------------------------------------------------------------------
// Prep kernels (unchanged)
// ---------------------------------------------------------------------------
__global__ __launch_bounds__(256) void k_prep_wih(const float* __restrict__ wf,
    const float* __restrict__ wb, _Float16* __restrict__ Bt,
    int KIN, int KP, int total)
{
  int idx = blockIdx.x * 256 + threadIdx.x;
  if (idx >= total) return;
  int n = idx / KP, k = idx % KP;
  int dd = n >> 10, nn = n & 1023;
  int row = (nn & 3) * 256 + (nn >> 2);
  const float* src = dd ? wb : wf;
  Bt[idx] = (_Float16)(k < KIN ? src[row * KIN + k] : 0.f);
}

__global__ __launch_bounds__(256) void k_prep_whh(const float* __restrict__ wf,
    const float* __restrict__ wb, _Float16* __restrict__ Wr)
{
  int idx = blockIdx.x * 256 + threadIdx.x;     // 0 .. 2*1024*256-1
  int dd = idx >> 18;
  int rem = idx & 262143;
  int n = rem >> 8, k = rem & 255;
  int row = (n & 3) * 256 + (n >> 2);
  Wr[idx] = (_Float16)((dd ? wb : wf)[row * 256 + k]);
}

__global__ void k_prep_bias(const float* __restrict__ bif, const float* __restrict__ bhf,
    const float* __restrict__ bib, const float* __restrict__ bhb, float* __restrict__ bias)
{
  int n = blockIdx.x * 256 + threadIdx.x;       // 0..2047
  int dd = n >> 10, nn = n & 1023;
  int row = (nn & 3) * 256 + (nn >> 2);
  bias[n] = dd ? (bib[row] + bhb[row]) : (bif[row] + bhf[row]);
}

__global__ __launch_bounds__(256) void k_gather(const int* __restrict__ ids,
    const float* __restrict__ emb, _Float16* __restrict__ xbf)
{
  int idx = blockIdx.x * 256 + threadIdx.x;     // T*40 threads, 8 f16 each
  int tt = idx / 40;
  int ch = idx % 40;
  int b = tt & 63, s = tt >> 6;
  int id = ids[b * S_ + s];
  const float* src = emb + (size_t)id * E_ + ch * 8;
  half8 v;
#pragma unroll
  for (int e = 0; e < 8; ++e) {
    int k = ch * 8 + e;
    v[e] = (_Float16)(k < E_ ? src[e] : 0.f);
  }
  *(half8*)(xbf + (size_t)tt * 320 + ch * 8) = v;
}

// ---------------------------------------------------------------------------
// Projection GEMM (unchanged): gx[d][t][b][n'] = A @ Bt^T + bias
// ---------------------------------------------------------------------------
template<int K>
__global__ __launch_bounds__(256) void k_gemm(const _Float16* __restrict__ A,
    const _Float16* __restrict__ Bt, const float* __restrict__ bias,
    _Float16* __restrict__ gx)
{
  __shared__ _Float16 sA[128 * 72];
  __shared__ _Float16 sB[128 * 72];
  const int tid = threadIdx.x;
  const int t0 = blockIdx.y * 128;
  const int n0 = blockIdx.x * 128;
  const int lane = tid & 63, wid = tid >> 6;
  const int l15 = lane & 15, q = lane >> 4;
  const int wm = wid & 1, wn = wid >> 1;

  float4v acc[4][4] = {};

  for (int kt = 0; kt < K / 64; ++kt) {
    __syncthreads();
#pragma unroll
    for (int c = 0; c < 4; ++c) {
      int f = tid * 4 + c;
      int row = f >> 3, seg = f & 7;
      *(half8*)&sA[row * 72 + seg * 8] =
          *(const half8*)(A + (size_t)(t0 + row) * K + kt * 64 + seg * 8);
      *(half8*)&sB[row * 72 + seg * 8] =
          *(const half8*)(Bt + (size_t)(n0 + row) * K + kt * 64 + seg * 8);
    }
    __syncthreads();
#pragma unroll
    for (int kk = 0; kk < 2; ++kk) {
      half8 a[4], b[4];
#pragma unroll
      for (int mt = 0; mt < 4; ++mt)
        a[mt] = *(const half8*)&sA[(wm * 64 + mt * 16 + l15) * 72 + kk * 32 + q * 8];
#pragma unroll
      for (int nt = 0; nt < 4; ++nt)
        b[nt] = *(const half8*)&sB[(wn * 64 + nt * 16 + l15) * 72 + kk * 32 + q * 8];
#pragma unroll
      for (int mt = 0; mt < 4; ++mt)
#pragma unroll
        for (int nt = 0; nt < 4; ++nt)
          acc[mt][nt] = __builtin_amdgcn_mfma_f32_16x16x32_f16(a[mt], b[nt], acc[mt][nt], 0, 0, 0);
    }
  }

#pragma unroll
  for (int mt = 0; mt < 4; ++mt) {
#pragma unroll
    for (int nt = 0; nt < 4; ++nt) {
      int token = t0 + wm * 64 + mt * 16 + q * 4;
      int n = n0 + wn * 64 + nt * 16 + l15;
      float bs = bias[n];
      size_t base = (size_t)(n >> 10) * ((size_t)T_ * G4H) + (size_t)token * G4H + (n & 1023);
#pragma unroll
      for (int r = 0; r < 4; ++r)
        gx[base + (size_t)r * G4H] = (_Float16)(acc[mt][nt][r] + bs);
    }
  }
}

// ---------------------------------------------------------------------------
// Persistent recurrence, fan-in 4, with HW-VERIFIED XCD co-location.
// Launch 256 blocks; each reads its physical XCD (s_getreg XCC_ID) and
// claims one of 4 role slots there: chain cg = XCD, quarter rg = slot.
// Surplus blocks wait for all 32 roles filled (rescue-adopts any deficit
// after a grace period -> no deadlock on any placement), then exit.
// => each chain's 4 blocks share one XCD; sc0 exchange rides that L2.
// Dual channel (sc0 fast + relaxed agent slow) as R7/R8.
// ---------------------------------------------------------------------------
template<int LAYER>
__global__ __launch_bounds__(256, 1) void k_rec(const _Float16* __restrict__ gx,
    const _Float16* __restrict__ Wr, uint64_t* __restrict__ hxf,
    uint64_t* __restrict__ hxs, _Float16* __restrict__ h1bf,
    float* __restrict__ pd2, const float* __restrict__ w_lin,
    int* __restrict__ claim)
{
  const int tid = threadIdx.x;
  __shared__ int role_sh;

  if (tid == 0) {
    int xcd = xcc_id();
    int slot = __hip_atomic_fetch_add(claim + xcd, 1, __ATOMIC_RELAXED,
                                      __HIP_MEMORY_SCOPE_AGENT);
    int role = -1;
    if (slot < 4) {
      role = xcd * 4 + slot;
    } else {
      // surplus: wait until all 32 roles filled; rescue-adopt a deficit
      for (int it = 0;; ++it) {
        int s = 0, deficit = -1;
        for (int x = 0; x < 8; ++x) {
          int v = __hip_atomic_load(claim + x, __ATOMIC_RELAXED,
                                    __HIP_MEMORY_SCOPE_AGENT);
          s += (v < 4 ? v : 4);
          if (v < 4) deficit = x;
        }
        if (s == 32) break;
        if (it > 8 && deficit >= 0) {
          int r = __hip_atomic_fetch_add(claim + deficit, 1, __ATOMIC_RELAXED,
                                         __HIP_MEMORY_SCOPE_AGENT);
          if (r < 4) { role = deficit * 4 + r; break; }
        }
        __builtin_amdgcn_s_sleep(64);
      }
    }
    role_sh = role;
  }
  __syncthreads();
  const int role = role_sh;
  if (role < 0) return;                       // surplus block exits

  const int cg = role >> 2, rg = role & 3;    // chain cg on THIS XCD
  const int d = cg >> 2, g = cg & 3;
  const int lane = tid & 63, wv = tid >> 6;
  const int l15 = lane & 15, q = lane >> 4;
  const int b0g = g * 16;           // global batch base
  const int n0g = rg * 256;         // gate-row base within direction

  __shared__ _Float16 hstage[16 * 288];   // h(t) [b 16][k 256], pad->288
  __shared__ float    preS[16 * 260];     // preact [b 16][row 256], pad->260

  for (int i = tid; i < 16 * 144; i += 256)
    ((uint32_t*)hstage)[i] = 0u;

  // ---- weight fragments: asm-def loads -> register/AGPR resident ----
  uint4 wreg[4][8];
#pragma unroll
  for (int nt = 0; nt < 4; ++nt)
#pragma unroll
    for (int kt = 0; kt < 8; ++kt)
      wreg[nt][kt] = ldx4_pin(Wr +
          (size_t)(d * G4H + n0g + wv * 64 + nt * 16 + l15) * H_ + kt * 32 + q * 8);

  // epilogue-role constants
  const int bl = tid >> 4;
  const int jl4 = (tid & 15) * 4;
  const int bglob = b0g + bl;
  const int jg = rg * 64 + jl4;
  float wl[4];
#pragma unroll
  for (int cc = 0; cc < 4; ++cc) wl[cc] = w_lin[jg + cc];
  float creg[4] = {0.f, 0.f, 0.f, 0.f};

  uint64_t* fbase = hxf + (size_t)cg * 2 * 2048;
  uint64_t* sbase = hxs + (size_t)cg * 2 * 2048;
  const int off2 = tid * 2;
  const int q2a = (rg + 1) & 3, q2b = (rg + 2) & 3, q2c = (rg + 3) & 3;

  // gx pipeline: step-0 value up front
  half8 gxa, gxb;
  {
    const int time0 = d ? (S_ - 1) : 0;
    const _Float16* gp = gx + ((size_t)d * T_ + (size_t)time0 * B_ + bglob) * G4H
                           + n0g + (tid & 15) * 16;
    gxa = *(const half8*)(gp);
    gxb = *(const half8*)(gp + 8);
  }

  for (int t = 0; t < S_; ++t) {
    const int time = d ? (S_ - 1 - t) : t;

    if (t > 0) {
      const uint64_t* fs = fbase + (size_t)(t & 1) * 2048;
      const uint64_t* ss = sbase + (size_t)(t & 1) * 2048;
      const uint32_t tt = (uint32_t)t;
      uint32_t dat[6];
      unsigned pend = 0x3fu;
      int round = 0;
      while (pend) {
        uint4 A, Bv, C;
        ld3_sc0(fs + q2a * 512 + off2, fs + q2b * 512 + off2,
                fs + q2c * 512 + off2, A, Bv, C);
        if ((pend & 1u)  && A.y  == tt) { dat[0] = A.x;  pend &= ~1u; }
        if ((pend & 2u)  && A.w  == tt) { dat[1] = A.z;  pend &= ~2u; }
        if ((pend & 4u)  && Bv.y == tt) { dat[2] = Bv.x; pend &= ~4u; }
        if ((pend & 8u)  && Bv.w == tt) { dat[3] = Bv.z; pend &= ~8u; }
        if ((pend & 16u) && C.y  == tt) { dat[4] = C.x;  pend &= ~16u; }
        if ((pend & 32u) && C.w  == tt) { dat[5] = C.z;  pend &= ~32u; }
        if (pend && ((++round & 3) == 0)) {
          const int wq[3] = {q2a, q2b, q2c};
#pragma unroll
          for (int k3 = 0; k3 < 3; ++k3)
#pragma unroll
            for (int j = 0; j < 2; ++j) {
              int w = k3 * 2 + j;
              if (pend & (1u << w)) {
                uint64_t v = __hip_atomic_load(ss + wq[k3] * 512 + off2 + j,
                                               __ATOMIC_RELAXED, __HIP_MEMORY_SCOPE_AGENT);
                if ((uint32_t)(v >> 32) == tt) { dat[w] = (uint32_t)v; pend &= ~(1u << w); }
              }
            }
        }
      }
      const int sb = tid >> 4, jp = (tid & 15) * 2;
      uint2 va; va.x = dat[0]; va.y = dat[1];
      uint2 vb; vb.x = dat[2]; vb.y = dat[3];
      uint2 vc; vc.x = dat[4]; vc.y = dat[5];
      *(uint2*)&((uint32_t*)hstage)[sb * 144 + q2a * 32 + jp] = va;
      *(uint2*)&((uint32_t*)hstage)[sb * 144 + q2b * 32 + jp] = vb;
      *(uint2*)&((uint32_t*)hstage)[sb * 144 + q2c * 32 + jp] = vc;
    }
    BARRIER();   // hstage complete

    // prefetch gx(t+1)
    half8 gxa_n, gxb_n;
    {
      const int tn = (t + 1 < S_) ? t + 1 : t;
      const int timen = d ? (S_ - 1 - tn) : tn;
      const _Float16* gp = gx + ((size_t)d * T_ + (size_t)timen * B_ + bglob) * G4H
                             + n0g + (tid & 15) * 16;
      gxa_n = *(const half8*)(gp);
      gxb_n = *(const half8*)(gp + 8);
    }

    // MFMA: pre[b 16][rows 256] = h(t) @ Wq^T
    float4v acc[4] = {};
#pragma unroll
    for (int kt = 0; kt < 8; ++kt) {
      half8 a = *(const half8*)&hstage[l15 * 288 + kt * 32 + q * 8];
#pragma unroll
      for (int nt = 0; nt < 4; ++nt)
        acc[nt] = __builtin_amdgcn_mfma_f32_16x16x32_f16(
            a, __builtin_bit_cast(half8, wreg[nt][kt]), acc[nt], 0, 0, 0);
    }
#pragma unroll
    for (int nt = 0; nt < 4; ++nt)
#pragma unroll
      for (int r = 0; r < 4; ++r)
        preS[(q * 4 + r) * 260 + wv * 64 + nt * 16 + l15] = acc[nt][r];
    BARRIER();

    // epilogue: 4 cells per thread
    half4 hv4;
    float partial = 0.f;
#pragma unroll
    for (int cc = 0; cc < 4; ++cc) {
      float4v p = *(const float4v*)&preS[bl * 260 + (jl4 + cc) * 4];
      float gxi = (float)(cc < 2 ? gxa[cc * 4 + 0] : gxb[(cc - 2) * 4 + 0]);
      float gxf = (float)(cc < 2 ? gxa[cc * 4 + 1] : gxb[(cc - 2) * 4 + 1]);
      float gxg = (float)(cc < 2 ? gxa[cc * 4 + 2] : gxb[(cc - 2) * 4 + 2]);
      float gxo = (float)(cc < 2 ? gxa[cc * 4 + 3] : gxb[(cc - 2) * 4 + 3]);
      float gi = p[0] + gxi, gf = p[1] + gxf, gg = p[2] + gxg, go = p[3] + gxo;
      float cv = sigm(gf) * creg[cc] + sigm(gi) * tanhf_(gg);
      float hv = sigm(go) * tanhf_(cv);
      creg[cc] = cv;
      hv4[cc] = (_Float16)hv;
      if (LAYER == 1) partial += 0.5f * hv * wl[cc];
    }

    // publish: fast 2x8B sc0 (local L2) + slow 2x8B agent (L3 fallback)
    {
      H2 p0; p0.h[0] = hv4[0]; p0.h[1] = hv4[1];
      H2 p1; p1.h[0] = hv4[2]; p1.h[1] = hv4[3];
      uint32_t tg = (uint32_t)(t + 1);
      uint64_t w0 = ((uint64_t)tg << 32) | p0.u;
      uint64_t w1 = ((uint64_t)tg << 32) | p1.u;
      uint64_t* fd = fbase + (size_t)((t + 1) & 1) * 2048 + rg * 512 + off2;
      st_sc0(fd + 0, w0);
      st_sc0(fd + 1, w1);
      uint64_t* sd = sbase + (size_t)((t + 1) & 1) * 2048 + rg * 512 + off2;
      __hip_atomic_store(sd + 0, w0, __ATOMIC_RELAXED, __HIP_MEMORY_SCOPE_AGENT);
      __hip_atomic_store(sd + 1, w1, __ATOMIC_RELAXED, __HIP_MEMORY_SCOPE_AGENT);
    }

    *(half4*)&hstage[bl * 288 + jg] = hv4;

    if (LAYER == 0) {
      *(half4*)(h1bf + ((size_t)time * B_ + bglob) * 512 + d * H_ + jg) = hv4;
    } else {
      partial += __shfl_xor(partial, 1);
      partial += __shfl_xor(partial, 2);
      partial += __shfl_xor(partial, 4);
      partial += __shfl_xor(partial, 8);
      if ((tid & 15) == 0)
        atomicAdd(pd2 + ((size_t)d * B_ + bglob) * S_ + time, partial);
    }

    gxa = gxa_n; gxb = gxb_n;
  }
}

// scores + masked-MSE loss
__global__ __launch_bounds__(256) void k_final(const float* __restrict__ pd2,
    const float* __restrict__ labels, const int* __restrict__ masks,
    const float* __restrict__ b_lin, float* __restrict__ out)
{
  int b = blockIdx.x;
  int tid = threadIdx.x;
  float bl = b_lin[0];
  float se = 0.f, sm = 0.f;
  for (int s = tid; s < S_; s += 256) {
    float p = pd2[(size_t)b * S_ + s] + pd2[(size_t)(B_ + b) * S_ + s];
    float sc = sigm(p + bl);
    out[b * S_ + s] = sc;
    float m = (float)masks[b * S_ + s];
    float e = sc - labels[b * S_ + s];
    se += e * e * m;
    sm += m;
  }
  for (int off = 1; off < 64; off <<= 1) {
    se += __shfl_xor(se, off);
    sm += __shfl_xor(sm, off);
  }
  __shared__ float rs[4], rm[4];
  int wid = tid >> 6;
  if ((tid & 63) == 0) { rs[wid] = se; rm[wid] = sm; }
  __syncthreads();
  if (tid == 0) {
    float te = 0.f, tm = 0.f;
    for (int w = 0; w < 4; ++w) { te += rs[w]; tm += rm[w]; }
    atomicAdd(out + T_, (te / tm) * (1.f / 64.f));
  }
}

// ---------------------------------------------------------------------------
extern "C" void kernel_launch(void* const* d_in, const int* in_sizes, int n_in,
                              void* d_out, int out_size, void* d_ws, size_t ws_size,
                              hipStream_t stream)
{
  (void)in_sizes; (void)n_in; (void)out_size; (void)ws_size;
  const int*   ids    = (const int*)d_in[0];
  const float* labels = (const float*)d_in[1];
  const int*   masks  = (const int*)d_in[2];
  const float* emb    = (const float*)d_in[3];
  const float* w_ih_0f = (const float*)d_in[4];
  const float* w_hh_0f = (const float*)d_in[5];
  const float* b_ih_0f = (const float*)d_in[6];
  const float* b_hh_0f = (const float*)d_in[7];
  const float* w_ih_0b = (const float*)d_in[8];
  const float* w_hh_0b = (const float*)d_in[9];
  const float* b_ih_0b = (const float*)d_in[10];
  const float* b_hh_0b = (const float*)d_in[11];
  const float* w_ih_1f = (const float*)d_in[12];
  const float* w_hh_1f = (const float*)d_in[13];
  const float* b_ih_1f = (const float*)d_in[14];
  const float* b_hh_1f = (const float*)d_in[15];
  const float* w_ih_1b = (const float*)d_in[16];
  const float* w_hh_1b = (const float*)d_in[17];
  const float* b_ih_1b = (const float*)d_in[18];
  const float* b_hh_1b = (const float*)d_in[19];
  const float* w_lin   = (const float*)d_in[20];
  const float* b_lin   = (const float*)d_in[21];
  float* out = (float*)d_out;

  char* ws = (char*)d_ws;
  size_t off = 0;
  auto alloc = [&](size_t bytes) -> char* {
    char* p = ws + off;
    off += (bytes + 255) & ~(size_t)255;
    return p;
  };
  _Float16* xbf   = (_Float16*)alloc((size_t)T_ * 320 * 2);        // 21 MB
  _Float16* h1bf  = (_Float16*)alloc((size_t)T_ * 512 * 2);        // 33.5 MB
  _Float16* gx    = (_Float16*)alloc((size_t)2 * T_ * G4H * 2);    // 134 MB
  _Float16* Bt0   = (_Float16*)alloc((size_t)2048 * 320 * 2);
  _Float16* Bt1   = (_Float16*)alloc((size_t)2048 * 512 * 2);
  _Float16* Wr0   = (_Float16*)alloc((size_t)2 * G4H * H_ * 2);
  _Float16* Wr1   = (_Float16*)alloc((size_t)2 * G4H * H_ * 2);
  float*    bias0 = (float*)alloc(2048 * 4);
  float*    bias1 = (float*)alloc(2048 * 4);
  uint64_t* hxf0  = (uint64_t*)alloc((size_t)8 * 2 * 2048 * 8);    // 256 KB
  uint64_t* hxs0  = (uint64_t*)alloc((size_t)8 * 2 * 2048 * 8);
  uint64_t* hxf1  = (uint64_t*)alloc((size_t)8 * 2 * 2048 * 8);
  uint64_t* hxs1  = (uint64_t*)alloc((size_t)8 * 2 * 2048 * 8);
  float*    pd2   = (float*)alloc((size_t)2 * B_ * S_ * 4);        // 256 KB
  int*      claim0 = (int*)alloc(256);
  int*      claim1 = (int*)alloc(256);

  // prep
  k_prep_wih<<<(2048 * 320) / 256, 256, 0, stream>>>(w_ih_0f, w_ih_0b, Bt0, 300, 320, 2048 * 320);
  k_prep_wih<<<(2048 * 512) / 256, 256, 0, stream>>>(w_ih_1f, w_ih_1b, Bt1, 512, 512, 2048 * 512);
  k_prep_whh<<<524288 / 256, 256, 0, stream>>>(w_hh_0f, w_hh_0b, Wr0);
  k_prep_whh<<<524288 / 256, 256, 0, stream>>>(w_hh_1f, w_hh_1b, Wr1);
  k_prep_bias<<<8, 256, 0, stream>>>(b_ih_0f, b_hh_0f, b_ih_0b, b_hh_0b, bias0);
  k_prep_bias<<<8, 256, 0, stream>>>(b_ih_1f, b_hh_1f, b_ih_1b, b_hh_1b, bias1);
  k_gather<<<(T_ * 40) / 256, 256, 0, stream>>>(ids, emb, xbf);

  hipMemsetAsync(hxf0, 0, (size_t)8 * 2 * 2048 * 8, stream);
  hipMemsetAsync(hxs0, 0, (size_t)8 * 2 * 2048 * 8, stream);
  hipMemsetAsync(hxf1, 0, (size_t)8 * 2 * 2048 * 8, stream);
  hipMemsetAsync(hxs1, 0, (size_t)8 * 2 * 2048 * 8, stream);
  hipMemsetAsync(pd2, 0, (size_t)2 * B_ * S_ * 4, stream);
  hipMemsetAsync(claim0, 0, 256, stream);
  hipMemsetAsync(claim1, 0, 256, stream);
  hipMemsetAsync((char*)d_out + (size_t)T_ * 4, 0, 4, stream);

  // layer 0
  k_gemm<320><<<dim3(16, 256), 256, 0, stream>>>(xbf, Bt0, bias0, gx);
  k_rec<0><<<256, 256, 0, stream>>>(gx, Wr0, hxf0, hxs0, h1bf, pd2, w_lin, claim0);

  // layer 1
  k_gemm<512><<<dim3(16, 256), 256, 0, stream>>>(h1bf, Bt1, bias1, gx);
  k_rec<1><<<256, 256, 0, stream>>>(gx, Wr1, hxf1, hxs1, h1bf, pd2, w_lin, claim1);

  k_final<<<64, 256, 0, stream>>>(pd2, labels, masks, b_lin, out);
}